// Round 3
// baseline (961.665 us; speedup 1.0000x reference)
//
#include <hip/hip_runtime.h>
#include <hip/hip_bf16.h>

typedef __bf16 bf16;
typedef __attribute__((ext_vector_type(8))) __bf16 bf16x8;
typedef __attribute__((ext_vector_type(4))) float f32x4;

#define E_TOTAL   1000000
#define NODE_DIM  128
#define EDGE_DIM  64
#define K1        320   // 2*128 + 64
#define N1        256
#define N2        128
#define N3        64

// LDS strides in elements (bf16): multiples of 8 (16B-aligned rows), ≡4 dwords
// mod 32 → only 2-way bank aliasing (free on gfx950, m136).
#define SA_STRIDE  72
#define SH1_STRIDE 264
#define SH2_STRIDE 136
#define SH3_STRIDE 72

// d_ws layout (bytes):
//   [0      , 163840) W1t bf16 [256][320]
//   [163840 , 229376) W2t bf16 [128][256]
//   [229376 , 245760) W3t bf16 [64][128]
//   [245760 , 247812) cano fp32[513] = b1[256] b2[128] b3[64] b4[1] W4[64]
//   [247812 , 247828) flags int[4] = {x_is_fp32, ef_is_fp32, w_is_fp32, ei_is_i64}
#define WS_W2T_OFF   163840
#define WS_W3T_OFF   229376
#define WS_CANO_OFF  245760
#define WS_FLAGS_OFF 247812

// ---------------------------------------------------------------------------
// Dtype sniffing (runtime guard; round-1 NaN already proved floats are fp32,
// but this keeps us correct under either storage).
// ---------------------------------------------------------------------------
__device__ inline int plausible16(const unsigned short* h) {
    int c = 0;
    for (int i = 0; i < 64; ++i) {
        int e = (h[i] >> 7) & 0xFF;
        if (e >= 90 && e <= 151) ++c;
    }
    return c;
}

__global__ void sniff(const void* x, const void* ei, const void* ef,
                      const void* W1, int* flags) {
    if (threadIdx.x == 0 && blockIdx.x == 0) {
        flags[0] = (plausible16((const unsigned short*)x)  < 52) ? 1 : 0;
        flags[1] = (plausible16((const unsigned short*)ef) < 52) ? 1 : 0;
        flags[2] = (plausible16((const unsigned short*)W1) < 52) ? 1 : 0;
        const int* w = (const int*)ei;
        int oz = 0, lo_ok = 1;
        for (int i = 1; i < 32; i += 2) if (w[i] == 0) ++oz;
        for (int i = 0; i < 32; i += 2) if ((unsigned)w[i] >= 100000u) lo_ok = 0;
        flags[3] = (oz == 16 && lo_ok) ? 1 : 0;
    }
}

__device__ inline float loadF(const void* p, int isf, int i) {
    return isf ? ((const float*)p)[i] : (float)((const bf16*)p)[i];
}

// Transpose W1/W2/W3 into k-contiguous bf16 (MFMA B-fragments = 16B loads),
// canonicalize biases + W4 to fp32.
__global__ void canonicalize(const void* W1, const void* W2, const void* W3,
                             const void* b1, const void* b2, const void* b3,
                             const void* W4, const void* b4,
                             bf16* W1t, bf16* W2t, bf16* W3t,
                             float* cano, const int* flags) {
    int isf = flags[2];
    int i = blockIdx.x * 256 + threadIdx.x;
    if (i < 81920) {                       // W1 [320][256]
        int k = i >> 8, n = i & 255;
        W1t[n * K1 + k] = (bf16)loadF(W1, isf, i);
    } else if (i < 114688) {               // W2 [256][128]
        int j = i - 81920, k = j >> 7, n = j & 127;
        W2t[n * N1 + k] = (bf16)loadF(W2, isf, j);
    } else if (i < 122880) {               // W3 [128][64]
        int j = i - 114688, k = j >> 6, n = j & 63;
        W3t[n * N2 + k] = (bf16)loadF(W3, isf, j);
    } else if (i < 123393) {               // biases + W4 → fp32
        int j = i - 122880;
        float v;
        if (j < 256)       v = loadF(b1, isf, j);
        else if (j < 384)  v = loadF(b2, isf, j - 256);
        else if (j < 448)  v = loadF(b3, isf, j - 384);
        else if (j == 448) v = loadF(b4, isf, 0);
        else               v = loadF(W4, isf, j - 449);
        cano[j] = v;
    }
}

// Staging task t (t in [0,512)) of K-chunk c: row = t>>3 (edge in tile),
// seg = t&7 (8-element segment).
__device__ inline bf16x8 stage_load(int c, int t, int e0,
                                    const void* __restrict__ x,
                                    const int* __restrict__ ei,
                                    const void* __restrict__ ef,
                                    int isfx, int isfe, int is64) {
    int row = t >> 3;
    int seg = t & 7;
    int e   = e0 + row;
    int kg  = (c << 6) + (seg << 3);      // global k in [0,320)
    const void* base;
    size_t idx;
    int isf;
    if (c < 4) {
        size_t pos = (c < 2) ? (size_t)e : (size_t)(E_TOTAL + e);
        int node = is64 ? ei[2 * pos] : ei[pos];
        base = x; idx = (size_t)node * NODE_DIM + (kg & 127); isf = isfx;
    } else {
        base = ef; idx = (size_t)e * EDGE_DIM + (kg - 256); isf = isfe;
    }
    if (isf) {
        const float* f = (const float*)base + idx;
        bf16x8 r;
#pragma unroll
        for (int i = 0; i < 8; ++i) r[i] = (bf16)f[i];
        return r;
    }
    return *(const bf16x8*)((const bf16*)base + idx);
}

// ---------------------------------------------------------------------------
// Fused MLP: one block = 64 edges; 4 waves, wave w owns a column slab.
// MFMA 16x16x32 bf16 layouts (learn_hip verified):
//   A: lane holds A[m = lane&15][k = (lane>>4)*8 + j]
//   B: lane holds B[k = (lane>>4)*8 + j][n = lane&15]
//   C/D: lane reg r holds D[row = (lane>>4)*4 + r][col = lane&15]
// Output: fp32 (reference returns float32; inputs proven fp32 in round 1-2).
// ---------------------------------------------------------------------------
__global__ __launch_bounds__(256, 2) void fused_mlp(
    const void* __restrict__ x, const int* __restrict__ ei, const void* __restrict__ ef,
    const bf16* __restrict__ W1t, const bf16* __restrict__ W2t,
    const bf16* __restrict__ W3t,
    const float* __restrict__ cano, const int* __restrict__ flags,
    float* __restrict__ out)
{
    __shared__ __align__(16) char smem[60416];
    bf16* sA  = (bf16*)smem;                    // [64][SA_STRIDE]
    bf16* sH1 = (bf16*)(smem + 9216);           // [64][SH1_STRIDE]
    bf16* sH2 = (bf16*)(smem + 9216 + 33792);   // [64][SH2_STRIDE]
    bf16* sH3 = sA;                             // aliases sA (dead after GEMM1)

    const int tid  = threadIdx.x;
    const int wave = tid >> 6;
    const int lane = tid & 63;
    const int quad = lane >> 4;
    const int l16  = lane & 15;
    const int e0   = blockIdx.x * 64;

    const int isfx = flags[0];
    const int isfe = flags[1];
    const int is64 = flags[3];

    // ---------------- GEMM1: [64,320] x [320,256] -> sH1 ----------------
    f32x4 acc1[4][4];
#pragma unroll
    for (int i = 0; i < 4; ++i)
#pragma unroll
        for (int j = 0; j < 4; ++j)
            acc1[i][j] = (f32x4){0.f, 0.f, 0.f, 0.f};

    bf16x8 pf0 = stage_load(0, tid,       e0, x, ei, ef, isfx, isfe, is64);
    bf16x8 pf1 = stage_load(0, tid + 256, e0, x, ei, ef, isfx, isfe, is64);

    for (int c = 0; c < 5; ++c) {
        __syncthreads();   // all waves done reading previous sA chunk
        *(bf16x8*)&sA[(tid >> 3) * SA_STRIDE + (tid & 7) * 8]           = pf0;
        *(bf16x8*)&sA[((tid + 256) >> 3) * SA_STRIDE + (tid & 7) * 8]   = pf1;
        __syncthreads();
        if (c < 4) {
            pf0 = stage_load(c + 1, tid,       e0, x, ei, ef, isfx, isfe, is64);
            pf1 = stage_load(c + 1, tid + 256, e0, x, ei, ef, isfx, isfe, is64);
        }
#pragma unroll
        for (int kk = 0; kk < 64; kk += 32) {
            bf16x8 a[4], b[4];
#pragma unroll
            for (int i = 0; i < 4; ++i)
                a[i] = *(const bf16x8*)&sA[(16 * i + l16) * SA_STRIDE + kk + quad * 8];
#pragma unroll
            for (int j = 0; j < 4; ++j)
                b[j] = *(const bf16x8*)&W1t[(size_t)(64 * wave + 16 * j + l16) * K1
                                            + (c * 64 + kk) + quad * 8];
#pragma unroll
            for (int i = 0; i < 4; ++i)
#pragma unroll
                for (int j = 0; j < 4; ++j)
                    acc1[i][j] = __builtin_amdgcn_mfma_f32_16x16x32_bf16(
                        a[i], b[j], acc1[i][j], 0, 0, 0);
        }
    }

    {   // epilogue 1: bias + relu -> sH1
        float bias[4];
#pragma unroll
        for (int j = 0; j < 4; ++j) bias[j] = cano[64 * wave + 16 * j + l16];
#pragma unroll
        for (int i = 0; i < 4; ++i)
#pragma unroll
            for (int r = 0; r < 4; ++r) {
                int m = 16 * i + quad * 4 + r;
#pragma unroll
                for (int j = 0; j < 4; ++j) {
                    float v = fmaxf(acc1[i][j][r] + bias[j], 0.f);
                    sH1[m * SH1_STRIDE + 64 * wave + 16 * j + l16] = (bf16)v;
                }
            }
    }
    __syncthreads();

    // ---------------- GEMM2: [64,256] x [256,128] -> sH2 ----------------
    f32x4 acc2[4][2];
#pragma unroll
    for (int i = 0; i < 4; ++i)
#pragma unroll
        for (int j = 0; j < 2; ++j)
            acc2[i][j] = (f32x4){0.f, 0.f, 0.f, 0.f};
#pragma unroll
    for (int ks = 0; ks < 8; ++ks) {
        int k0 = ks * 32;
        bf16x8 a[4], b[2];
#pragma unroll
        for (int i = 0; i < 4; ++i)
            a[i] = *(const bf16x8*)&sH1[(16 * i + l16) * SH1_STRIDE + k0 + quad * 8];
#pragma unroll
        for (int j = 0; j < 2; ++j)
            b[j] = *(const bf16x8*)&W2t[(size_t)(32 * wave + 16 * j + l16) * N1 + k0 + quad * 8];
#pragma unroll
        for (int i = 0; i < 4; ++i)
#pragma unroll
            for (int j = 0; j < 2; ++j)
                acc2[i][j] = __builtin_amdgcn_mfma_f32_16x16x32_bf16(
                    a[i], b[j], acc2[i][j], 0, 0, 0);
    }
    {
        float bias[2];
#pragma unroll
        for (int j = 0; j < 2; ++j) bias[j] = cano[256 + 32 * wave + 16 * j + l16];
#pragma unroll
        for (int i = 0; i < 4; ++i)
#pragma unroll
            for (int r = 0; r < 4; ++r) {
                int m = 16 * i + quad * 4 + r;
#pragma unroll
                for (int j = 0; j < 2; ++j) {
                    float v = fmaxf(acc2[i][j][r] + bias[j], 0.f);
                    sH2[m * SH2_STRIDE + 32 * wave + 16 * j + l16] = (bf16)v;
                }
            }
    }
    __syncthreads();

    // ---------------- GEMM3: [64,128] x [128,64] -> sH3 ----------------
    f32x4 acc3[4];
#pragma unroll
    for (int i = 0; i < 4; ++i) acc3[i] = (f32x4){0.f, 0.f, 0.f, 0.f};
#pragma unroll
    for (int ks = 0; ks < 4; ++ks) {
        int k0 = ks * 32;
        bf16x8 b = *(const bf16x8*)&W3t[(size_t)(16 * wave + l16) * N2 + k0 + quad * 8];
#pragma unroll
        for (int i = 0; i < 4; ++i) {
            bf16x8 a = *(const bf16x8*)&sH2[(16 * i + l16) * SH2_STRIDE + k0 + quad * 8];
            acc3[i] = __builtin_amdgcn_mfma_f32_16x16x32_bf16(a, b, acc3[i], 0, 0, 0);
        }
    }
    {
        float bias = cano[384 + 16 * wave + l16];
#pragma unroll
        for (int i = 0; i < 4; ++i)
#pragma unroll
            for (int r = 0; r < 4; ++r) {
                int m = 16 * i + quad * 4 + r;
                float v = fmaxf(acc3[i][r] + bias, 0.f);
                sH3[m * SH3_STRIDE + 16 * wave + l16] = (bf16)v;
            }
    }
    __syncthreads();

    // ---------------- Stage 4: [64,64] x [64,1] + b4 -> out (fp32) ----------
    if (tid < 64) {
        float s = cano[448];
#pragma unroll
        for (int k = 0; k < 64; ++k)
            s += (float)sH3[tid * SH3_STRIDE + k] * cano[449 + k];
        out[e0 + tid] = s;
    }
}

extern "C" void kernel_launch(void* const* d_in, const int* in_sizes, int n_in,
                              void* d_out, int out_size, void* d_ws, size_t ws_size,
                              hipStream_t stream) {
    const void* x  = d_in[0];
    const int*  ei = (const int*)d_in[1];
    const void* ef = d_in[2];
    // d_in[3] = num_nodes (unused)
    const void* W1 = d_in[4];
    const void* b1 = d_in[5];
    const void* W2 = d_in[6];
    const void* b2 = d_in[7];
    const void* W3 = d_in[8];
    const void* b3 = d_in[9];
    const void* W4 = d_in[10];
    const void* b4 = d_in[11];
    float* out = (float*)d_out;

    char* ws = (char*)d_ws;
    bf16*  W1t   = (bf16*)ws;
    bf16*  W2t   = (bf16*)(ws + WS_W2T_OFF);
    bf16*  W3t   = (bf16*)(ws + WS_W3T_OFF);
    float* cano  = (float*)(ws + WS_CANO_OFF);
    int*   flags = (int*)(ws + WS_FLAGS_OFF);

    sniff<<<1, 64, 0, stream>>>(x, ei, ef, W1, flags);
    canonicalize<<<483, 256, 0, stream>>>(W1, W2, W3, b1, b2, b3, W4, b4,
                                          W1t, W2t, W3t, cano, flags);
    fused_mlp<<<E_TOTAL / 64, 256, 0, stream>>>(x, ei, ef, W1t, W2t, W3t,
                                                cano, flags, out);
}

// Round 4
// 655.030 us; speedup vs baseline: 1.4681x; 1.4681x over previous
//
#include <hip/hip_runtime.h>
#include <hip/hip_bf16.h>

typedef __bf16 bf16;
typedef __attribute__((ext_vector_type(8))) __bf16 bf16x8;
typedef __attribute__((ext_vector_type(4))) float f32x4;

#define E_TOTAL   1000000
#define NODE_DIM  128
#define EDGE_DIM  64

// LDS strides (bf16 elems): multiples of 8 (16B rows), ≡4 dwords mod 32 →
// 2-way bank aliasing only (free on gfx950, m136).
#define SA_STRIDE  328   // 320 + 8
#define SH1_STRIDE 264   // 256 + 8
#define SH2_STRIDE 136   // 128 + 8
#define SH3_STRIDE 72    // 64 + 8

// ws layout, BIG mode (ws_size >= WS_NEED):
//   [0, 25600000)  xbf bf16[100000*128]
//   then W1f (163840 B), W2f (65536), W3f (16384), cano fp32[513] (2052), flags (16)
// SMALL mode: same minus xbf, weights at offset 0.
#define WS_XBF_BYTES 25600000
#define WB_W2F  163840
#define WB_W3F  (163840 + 65536)
#define WB_CANO (163840 + 65536 + 16384)
#define WB_FLAG (163840 + 65536 + 16384 + 2052)
#define WB_END  (163840 + 65536 + 16384 + 2052 + 16)
#define WS_NEED (WS_XBF_BYTES + WB_END)

// ---------------------------------------------------------------------------
// Dtype sniffing (fp32 proven empirically; keep as runtime guard).
// ---------------------------------------------------------------------------
__device__ inline int plausible16(const unsigned short* h) {
    int c = 0;
    for (int i = 0; i < 64; ++i) {
        int e = (h[i] >> 7) & 0xFF;
        if (e >= 90 && e <= 151) ++c;
    }
    return c;
}

__global__ void sniff(const void* x, const void* ei, const void* ef,
                      const void* W1, int* flags) {
    if (threadIdx.x == 0 && blockIdx.x == 0) {
        flags[0] = (plausible16((const unsigned short*)x)  < 52) ? 1 : 0;
        flags[1] = (plausible16((const unsigned short*)ef) < 52) ? 1 : 0;
        flags[2] = (plausible16((const unsigned short*)W1) < 52) ? 1 : 0;
        const int* w = (const int*)ei;
        int oz = 0, lo_ok = 1;
        for (int i = 1; i < 32; i += 2) if (w[i] == 0) ++oz;
        for (int i = 0; i < 32; i += 2) if ((unsigned)w[i] >= 100000u) lo_ok = 0;
        flags[3] = (oz == 16 && lo_ok) ? 1 : 0;
    }
}

__device__ inline float loadF(const void* p, int isf, int i) {
    return isf ? ((const float*)p)[i] : (float)((const bf16*)p)[i];
}

// ---------------------------------------------------------------------------
// Weights -> frag-major: W1f[((jt*10+ks)*64+lane)*8+jj] holds
// B[k=ks*32+(lane>>4)*8+jj][n=jt*16+(lane&15)] — a wave's B-frag load becomes
// one coalesced 1KB stream (was 16B/lane scattered = 4x L2 line waste).
// ---------------------------------------------------------------------------
__global__ void canonicalize(const void* W1, const void* W2, const void* W3,
                             const void* b1, const void* b2, const void* b3,
                             const void* W4, const void* b4,
                             bf16* W1f, bf16* W2f, bf16* W3f,
                             float* cano, const int* flags) {
    int isf = flags[2];
    int o = blockIdx.x * 256 + threadIdx.x;
    if (o < 81920) {                        // W1 [320][256] -> frag-major
        int jj = o & 7, lane = (o >> 3) & 63, t2 = o >> 9;
        int ks = t2 % 10, jt = t2 / 10;
        int k = ks * 32 + (lane >> 4) * 8 + jj;
        int n = jt * 16 + (lane & 15);
        W1f[o] = (bf16)loadF(W1, isf, k * 256 + n);
    } else if (o < 114688) {                // W2 [256][128]
        int o2 = o - 81920;
        int jj = o2 & 7, lane = (o2 >> 3) & 63, t2 = o2 >> 9;
        int ks = t2 & 7, jt = t2 >> 3;
        int k = ks * 32 + (lane >> 4) * 8 + jj;
        int n = jt * 16 + (lane & 15);
        W2f[o2] = (bf16)loadF(W2, isf, k * 128 + n);
    } else if (o < 122880) {                // W3 [128][64]
        int o3 = o - 114688;
        int jj = o3 & 7, lane = (o3 >> 3) & 63, t2 = o3 >> 9;
        int ks = t2 & 3, jt = t2 >> 2;
        int k = ks * 32 + (lane >> 4) * 8 + jj;
        int n = jt * 16 + (lane & 15);
        W3f[o3] = (bf16)loadF(W3, isf, k * 64 + n);
    } else if (o < 123393) {                // cano fp32: b1 b2 b3 b4 W4
        int j = o - 122880;
        float v;
        if (j < 256)       v = loadF(b1, isf, j);
        else if (j < 384)  v = loadF(b2, isf, j - 256);
        else if (j < 448)  v = loadF(b3, isf, j - 384);
        else if (j == 448) v = loadF(b4, isf, 0);
        else               v = loadF(W4, isf, j - 449);
        cano[j] = v;
    }
}

// x -> bf16 (halves gather bytes; x_bf16 = 25.6 MB ≈ L2-aggregate scale).
__global__ void convert_x(const void* x, bf16* xbf, const int* flags) {
    int i = (blockIdx.x * 256 + threadIdx.x) * 4;   // 12500 blocks covers 12.8M
    if (flags[0]) {
        const float* f = (const float*)x + i;
        bf16 v0 = (bf16)f[0], v1 = (bf16)f[1], v2 = (bf16)f[2], v3 = (bf16)f[3];
        xbf[i] = v0; xbf[i + 1] = v1; xbf[i + 2] = v2; xbf[i + 3] = v3;
    } else {
        *(unsigned long long*)(xbf + i) = *(const unsigned long long*)((const bf16*)x + i);
    }
}

// ---------------------------------------------------------------------------
// Fused MLP. One block = 64 edges, 4 waves, wave owns a 64/32/16-col slab.
// MFMA 16x16x32 bf16 layouts (learn_hip verified):
//   A: lane holds A[m=lane&15][k=(lane>>4)*8+j]
//   B: lane holds B[k=(lane>>4)*8+j][n=lane&15]
//   C/D: reg r holds D[row=(lane>>4)*4+r][col=lane&15]
// Full A-tile staged once (10 loads/thread in flight), 4 barriers total.
// ---------------------------------------------------------------------------
__global__ __launch_bounds__(256, 2) void fused_mlp(
    const void* __restrict__ xs, const int* __restrict__ ei, const void* __restrict__ ef,
    const bf16* __restrict__ W1f, const bf16* __restrict__ W2f,
    const bf16* __restrict__ W3f,
    const float* __restrict__ cano, const int* __restrict__ flags,
    int xmode_host, float* __restrict__ out)
{
    __shared__ __align__(16) char smem[75776];
    bf16* sA  = (bf16*)smem;                 // [64][328]  41984 B
    bf16* sH1 = (bf16*)(smem + 41984);       // [64][264]  33792 B
    bf16* sH2 = (bf16*)smem;                 // [64][136]  aliases dead sA
    bf16* sH3 = (bf16*)(smem + 17408);       // [64][72]   aliases sA tail

    const int tid  = threadIdx.x;
    const int wave = tid >> 6;
    const int lane = tid & 63;
    const int quad = lane >> 4;
    const int l16  = lane & 15;
    const int e0   = blockIdx.x * 64;

    const int isfe = flags[1];
    const int is64 = flags[3];
    const int xm   = (xmode_host < 0) ? flags[0] : xmode_host;

    // ---- stage full A-tile: x = 8 tasks/thread, ef = 2 tasks/thread ----
    {
        const int xrow0 = tid >> 5;          // rows i*8 + xrow0
        const int xseg  = tid & 31;          // k = xseg*8 (0..255)
        const int which = xseg >> 4;         // 0: v-endpoint, 1: u-endpoint
        const int xk    = (xseg & 15) << 3;  // k within node row
        if (xm == 0) {
            const bf16* xsb = (const bf16*)xs;
            bf16x8 xb[8];
#pragma unroll
            for (int i = 0; i < 8; ++i) {
                int row = i * 8 + xrow0;
                size_t pos = which ? (size_t)(E_TOTAL + e0 + row) : (size_t)(e0 + row);
                int node = is64 ? ei[2 * pos] : ei[pos];
                xb[i] = *(const bf16x8*)(xsb + (size_t)node * NODE_DIM + xk);
            }
#pragma unroll
            for (int i = 0; i < 8; ++i)
                *(bf16x8*)&sA[(i * 8 + xrow0) * SA_STRIDE + xseg * 8] = xb[i];
        } else {
            const float* xsf = (const float*)xs;
            float xf[8][8];
#pragma unroll
            for (int i = 0; i < 8; ++i) {
                int row = i * 8 + xrow0;
                size_t pos = which ? (size_t)(E_TOTAL + e0 + row) : (size_t)(e0 + row);
                int node = is64 ? ei[2 * pos] : ei[pos];
                const float* f = xsf + (size_t)node * NODE_DIM + xk;
#pragma unroll
                for (int j = 0; j < 8; ++j) xf[i][j] = f[j];
            }
#pragma unroll
            for (int i = 0; i < 8; ++i) {
                bf16x8 v;
#pragma unroll
                for (int j = 0; j < 8; ++j) v[j] = (bf16)xf[i][j];
                *(bf16x8*)&sA[(i * 8 + xrow0) * SA_STRIDE + xseg * 8] = v;
            }
        }
        // edge features: rows tid>>3 and +32, k = 256 + (tid&7)*8
        int seg = tid & 7, r0 = tid >> 3, r1 = r0 + 32;
        int kst = 256 + seg * 8;
        if (isfe) {
            const float* f0 = (const float*)ef + (size_t)(e0 + r0) * EDGE_DIM + seg * 8;
            const float* f1 = (const float*)ef + (size_t)(e0 + r1) * EDGE_DIM + seg * 8;
            float a0[8], a1[8];
#pragma unroll
            for (int j = 0; j < 8; ++j) { a0[j] = f0[j]; a1[j] = f1[j]; }
            bf16x8 v0, v1;
#pragma unroll
            for (int j = 0; j < 8; ++j) { v0[j] = (bf16)a0[j]; v1[j] = (bf16)a1[j]; }
            *(bf16x8*)&sA[r0 * SA_STRIDE + kst] = v0;
            *(bf16x8*)&sA[r1 * SA_STRIDE + kst] = v1;
        } else {
            const bf16* eb = (const bf16*)ef;
            bf16x8 v0 = *(const bf16x8*)(eb + (size_t)(e0 + r0) * EDGE_DIM + seg * 8);
            bf16x8 v1 = *(const bf16x8*)(eb + (size_t)(e0 + r1) * EDGE_DIM + seg * 8);
            *(bf16x8*)&sA[r0 * SA_STRIDE + kst] = v0;
            *(bf16x8*)&sA[r1 * SA_STRIDE + kst] = v1;
        }
    }
    __syncthreads();

    // ---------------- GEMM1: [64,320] x [320,256] -> sH1 ----------------
    f32x4 acc1[4][4];
#pragma unroll
    for (int i = 0; i < 4; ++i)
#pragma unroll
        for (int j = 0; j < 4; ++j)
            acc1[i][j] = (f32x4){0.f, 0.f, 0.f, 0.f};

    const bf16* w1base = W1f + (size_t)wave * (40 * 512) + lane * 8;
#pragma unroll
    for (int ks = 0; ks < 10; ++ks) {
        bf16x8 a[4], b[4];
#pragma unroll
        for (int j = 0; j < 4; ++j)
            b[j] = *(const bf16x8*)(w1base + (j * 10 + ks) * 512);
#pragma unroll
        for (int i = 0; i < 4; ++i)
            a[i] = *(const bf16x8*)&sA[(16 * i + l16) * SA_STRIDE + ks * 32 + quad * 8];
#pragma unroll
        for (int i = 0; i < 4; ++i)
#pragma unroll
            for (int j = 0; j < 4; ++j)
                acc1[i][j] = __builtin_amdgcn_mfma_f32_16x16x32_bf16(
                    a[i], b[j], acc1[i][j], 0, 0, 0);
    }
    {   // bias + relu -> sH1
        float bias[4];
#pragma unroll
        for (int j = 0; j < 4; ++j) bias[j] = cano[64 * wave + 16 * j + l16];
#pragma unroll
        for (int i = 0; i < 4; ++i)
#pragma unroll
            for (int r = 0; r < 4; ++r) {
                int m = 16 * i + quad * 4 + r;
#pragma unroll
                for (int j = 0; j < 4; ++j) {
                    float v = fmaxf(acc1[i][j][r] + bias[j], 0.f);
                    sH1[m * SH1_STRIDE + 64 * wave + 16 * j + l16] = (bf16)v;
                }
            }
    }
    __syncthreads();

    // ---------------- GEMM2: [64,256] x [256,128] -> sH2 ----------------
    f32x4 acc2[4][2];
#pragma unroll
    for (int i = 0; i < 4; ++i)
#pragma unroll
        for (int j = 0; j < 2; ++j)
            acc2[i][j] = (f32x4){0.f, 0.f, 0.f, 0.f};
    const bf16* w2base = W2f + (size_t)wave * (16 * 512) + lane * 8;
#pragma unroll
    for (int ks = 0; ks < 8; ++ks) {
        bf16x8 a[4], b[2];
#pragma unroll
        for (int j = 0; j < 2; ++j)
            b[j] = *(const bf16x8*)(w2base + (j * 8 + ks) * 512);
#pragma unroll
        for (int i = 0; i < 4; ++i)
            a[i] = *(const bf16x8*)&sH1[(16 * i + l16) * SH1_STRIDE + ks * 32 + quad * 8];
#pragma unroll
        for (int i = 0; i < 4; ++i)
#pragma unroll
            for (int j = 0; j < 2; ++j)
                acc2[i][j] = __builtin_amdgcn_mfma_f32_16x16x32_bf16(
                    a[i], b[j], acc2[i][j], 0, 0, 0);
    }
    {
        float bias[2];
#pragma unroll
        for (int j = 0; j < 2; ++j) bias[j] = cano[256 + 32 * wave + 16 * j + l16];
#pragma unroll
        for (int i = 0; i < 4; ++i)
#pragma unroll
            for (int r = 0; r < 4; ++r) {
                int m = 16 * i + quad * 4 + r;
#pragma unroll
                for (int j = 0; j < 2; ++j) {
                    float v = fmaxf(acc2[i][j][r] + bias[j], 0.f);
                    sH2[m * SH2_STRIDE + 32 * wave + 16 * j + l16] = (bf16)v;
                }
            }
    }
    __syncthreads();

    // ---------------- GEMM3: [64,128] x [128,64] -> sH3 ----------------
    f32x4 acc3[4];
#pragma unroll
    for (int i = 0; i < 4; ++i) acc3[i] = (f32x4){0.f, 0.f, 0.f, 0.f};
    const bf16* w3base = W3f + (size_t)wave * (4 * 512) + lane * 8;
#pragma unroll
    for (int ks = 0; ks < 4; ++ks) {
        bf16x8 b = *(const bf16x8*)(w3base + ks * 512);
#pragma unroll
        for (int i = 0; i < 4; ++i) {
            bf16x8 a = *(const bf16x8*)&sH2[(16 * i + l16) * SH2_STRIDE + ks * 32 + quad * 8];
            acc3[i] = __builtin_amdgcn_mfma_f32_16x16x32_bf16(a, b, acc3[i], 0, 0, 0);
        }
    }
    {
        float bias = cano[384 + 16 * wave + l16];
#pragma unroll
        for (int i = 0; i < 4; ++i)
#pragma unroll
            for (int r = 0; r < 4; ++r) {
                int m = 16 * i + quad * 4 + r;
                float v = fmaxf(acc3[i][r] + bias, 0.f);
                sH3[m * SH3_STRIDE + 16 * wave + l16] = (bf16)v;
            }
    }
    __syncthreads();

    // ---------------- Stage 4: h3[64] · W4 + b4 -> out (all threads) --------
    {
        int edge = tid >> 2;
        int part = tid & 3;
        int k0 = part * 16;
        const bf16* h = &sH3[edge * SH3_STRIDE + k0];
        float s = 0.f;
#pragma unroll
        for (int k = 0; k < 16; ++k)
            s += (float)h[k] * cano[449 + k0 + k];
        s += __shfl_xor(s, 1);
        s += __shfl_xor(s, 2);
        if (part == 0) out[e0 + edge] = s + cano[448];
    }
}

extern "C" void kernel_launch(void* const* d_in, const int* in_sizes, int n_in,
                              void* d_out, int out_size, void* d_ws, size_t ws_size,
                              hipStream_t stream) {
    const void* x  = d_in[0];
    const int*  ei = (const int*)d_in[1];
    const void* ef = d_in[2];
    const void* W1 = d_in[4];
    const void* b1 = d_in[5];
    const void* W2 = d_in[6];
    const void* b2 = d_in[7];
    const void* W3 = d_in[8];
    const void* b3 = d_in[9];
    const void* W4 = d_in[10];
    const void* b4 = d_in[11];
    float* out = (float*)d_out;

    char* ws = (char*)d_ws;
    const bool big = ws_size >= (size_t)WS_NEED;   // ws_size constant per session
    bf16* xbf   = (bf16*)ws;                       // BIG mode only
    char* wbase = big ? (ws + WS_XBF_BYTES) : ws;
    bf16*  W1f   = (bf16*)wbase;
    bf16*  W2f   = (bf16*)(wbase + WB_W2F);
    bf16*  W3f   = (bf16*)(wbase + WB_W3F);
    float* cano  = (float*)(wbase + WB_CANO);
    int*   flags = (int*)(wbase + WB_FLAG);

    sniff<<<1, 64, 0, stream>>>(x, ei, ef, W1, flags);
    canonicalize<<<483, 256, 0, stream>>>(W1, W2, W3, b1, b2, b3, W4, b4,
                                          W1f, W2f, W3f, cano, flags);
    if (big) convert_x<<<12500, 256, 0, stream>>>(x, xbf, flags);
    fused_mlp<<<E_TOTAL / 64, 256, 0, stream>>>(
        big ? (const void*)xbf : x, ei, ef, W1f, W2f, W3f,
        cano, flags, big ? 0 : -1, out);
}